// Round 1
// baseline (1329.527 us; speedup 1.0000x reference)
//
#include <hip/hip_runtime.h>
#include <cstddef>

#define S_LEN 2048
#define DK    7
#define TQ    16     // q rows per block
#define NT    256    // threads per block
#define KPT   8      // k rows per thread (256*8 = 2048)

__global__ __launch_bounds__(NT) void sdpa_kernel(
    const float* __restrict__ Q, const float* __restrict__ K,
    const float* __restrict__ V, float* __restrict__ ctxOut,
    float* __restrict__ attnOut)
{
    const int numQT = S_LEN / TQ;              // 128 q-tiles per (b,h)
    const int bh = blockIdx.x / numQT;
    const int q0 = (blockIdx.x % numQT) * TQ;
    const int t    = threadIdx.x;
    const int lane = t & 63;
    const int wave = t >> 6;

    __shared__ float qs[TQ * DK];              // pre-scaled Q tile (112 floats)
    __shared__ float redA[4];                  // per-wave max partials
    __shared__ float redB[4];                  // per-wave sum partials
    __shared__ float ctxred[4][DK];            // per-wave ctx partials

    const float scale = 0.3779644730092272f;   // 1/sqrt(7)

    // Stage Q tile into LDS, pre-scaled (broadcast reads later are free)
    if (t < TQ * DK) {
        qs[t] = Q[(size_t)bh * S_LEN * DK + (size_t)q0 * DK + t] * scale;
    }

    // Load this thread's 8 K rows and 8 V rows into registers.
    // 56 floats each = 14 aligned float4 loads (bh*S*DK*4 = 57344B, t*224B: both 16B-aligned).
    float kr[KPT * DK], vr[KPT * DK];
    {
        const float4* kp = reinterpret_cast<const float4*>(K + (size_t)bh * S_LEN * DK) + t * 14;
        const float4* vp = reinterpret_cast<const float4*>(V + (size_t)bh * S_LEN * DK) + t * 14;
        #pragma unroll
        for (int i = 0; i < 14; ++i) {
            float4 a = kp[i];
            kr[4*i+0] = a.x; kr[4*i+1] = a.y; kr[4*i+2] = a.z; kr[4*i+3] = a.w;
            float4 b = vp[i];
            vr[4*i+0] = b.x; vr[4*i+1] = b.y; vr[4*i+2] = b.z; vr[4*i+3] = b.w;
        }
    }
    __syncthreads();

    float* attnBH = attnOut + (size_t)bh * S_LEN * S_LEN;
    float* ctxBH  = ctxOut  + (size_t)bh * S_LEN * DK;

    for (int qi = 0; qi < TQ; ++qi) {
        const int q = q0 + qi;

        float qv[DK];
        #pragma unroll
        for (int d = 0; d < DK; ++d) qv[d] = qs[qi * DK + d];

        // scores for this thread's 8 k rows
        float s[KPT];
        #pragma unroll
        for (int j = 0; j < KPT; ++j) {
            float acc = 0.f;
            #pragma unroll
            for (int d = 0; d < DK; ++d) acc += kr[j*DK + d] * qv[d];
            s[j] = acc;
        }

        // ---- block max reduce ----
        float m = s[0];
        #pragma unroll
        for (int j = 1; j < KPT; ++j) m = fmaxf(m, s[j]);
        #pragma unroll
        for (int off = 32; off > 0; off >>= 1)
            m = fmaxf(m, __shfl_down(m, off, 64));
        if (lane == 0) redA[wave] = m;
        __syncthreads();                                       // bar A
        const float M = fmaxf(fmaxf(redA[0], redA[1]), fmaxf(redA[2], redA[3]));

        // ---- exp + block sum reduce ----
        float e[KPT];
        float lsum = 0.f;
        #pragma unroll
        for (int j = 0; j < KPT; ++j) { e[j] = __expf(s[j] - M); lsum += e[j]; }
        #pragma unroll
        for (int off = 32; off > 0; off >>= 1)
            lsum += __shfl_down(lsum, off, 64);
        if (lane == 0) redB[wave] = lsum;
        __syncthreads();                                       // bar B
        const float Sum = (redB[0] + redB[1]) + (redB[2] + redB[3]);
        const float inv = 1.0f / Sum;

        float p[KPT];
        #pragma unroll
        for (int j = 0; j < KPT; ++j) p[j] = e[j] * inv;

        // ---- coalesced attn row store (2 x float4 per thread) ----
        float4* rowp = reinterpret_cast<float4*>(attnBH + (size_t)q * S_LEN + t * KPT);
        rowp[0] = make_float4(p[0], p[1], p[2], p[3]);
        rowp[1] = make_float4(p[4], p[5], p[6], p[7]);

        // ---- context partials + block reduce of 7 floats ----
        float c[DK];
        #pragma unroll
        for (int d = 0; d < DK; ++d) {
            float acc = 0.f;
            #pragma unroll
            for (int j = 0; j < KPT; ++j) acc += p[j] * vr[j*DK + d];
            c[d] = acc;
        }
        #pragma unroll
        for (int d = 0; d < DK; ++d) {
            #pragma unroll
            for (int off = 32; off > 0; off >>= 1)
                c[d] += __shfl_down(c[d], off, 64);
        }
        if (lane == 0) {
            #pragma unroll
            for (int d = 0; d < DK; ++d) ctxred[wave][d] = c[d];
        }
        __syncthreads();                                       // bar C
        if (t < DK) {
            ctxBH[(size_t)q * DK + t] =
                ctxred[0][t] + ctxred[1][t] + ctxred[2][t] + ctxred[3][t];
        }
        // LDS reuse hazards are fenced: any rewrite of redA/redB/ctxred in
        // iteration qi+1 happens only after a barrier that all readers of
        // iteration qi have already crossed.
    }
}

extern "C" void kernel_launch(void* const* d_in, const int* in_sizes, int n_in,
                              void* d_out, int out_size, void* d_ws, size_t ws_size,
                              hipStream_t stream) {
    const float* Q = (const float*)d_in[0];
    const float* K = (const float*)d_in[1];
    const float* V = (const float*)d_in[2];
    float* out = (float*)d_out;

    const int BH = in_sizes[0] / (S_LEN * DK);          // 64
    float* ctxOut  = out;                               // [BH, S, 7]
    float* attnOut = out + (size_t)BH * S_LEN * DK;     // [BH, S, S]

    dim3 grid(BH * (S_LEN / TQ));                       // 8192 blocks
    sdpa_kernel<<<grid, NT, 0, stream>>>(Q, K, V, ctxOut, attnOut);
}